// Round 12
// baseline (208.468 us; speedup 1.0000x reference)
//
#include <hip/hip_runtime.h>

#define NN 100000
#define NE 1600000

// bucketed counting sort params: 512 nodes per bucket
#define BSH 9
#define BSZ 512
#define NBUK 196          // ceil(NN / BSZ)
#define CAP 12288         // per-bucket pair capacity (mean 8163, huge margin)
#define CHUNK 4096        // edges per block in bucket phase
#define EPT 16            // edges per thread (CHUNK/256)

typedef _Float16 hs8 __attribute__((ext_vector_type(8)));
typedef float f32x4 __attribute__((ext_vector_type(4)));
typedef float f32x2 __attribute__((ext_vector_type(2)));
#define MFMA16H(a, b, c) __builtin_amdgcn_mfma_f32_16x16x32_f16(a, b, c, 0, 0, 0)

static inline size_t alignup(size_t x) { return (x + 255) & ~(size_t)255; }

union h8u { uint4 q; _Float16 h[8]; };

// ---------------- prep0: control init + W converts ----------------
// gctl[0] = CSR allocation cursor, gctl[16] = grid barrier counter

__global__ __launch_bounds__(256) void k_prep0(int* __restrict__ gcur, int* __restrict__ gctl,
                                               const float* __restrict__ W1, _Float16* __restrict__ WT1,
                                               const float* __restrict__ W2, _Float16* __restrict__ WT2) {
  int b = blockIdx.x, t = threadIdx.x;
  if (b < 64) {  // W1: [128,128] -> WT1[c][k]
    int i = b * 256 + t;
    int k = i >> 7, c = i & 127;
    WT1[c * 128 + k] = (_Float16)W1[i];
  } else if (b < 96) {  // W2: [128,64] -> WT2[c][k]
    int i = (b - 64) * 256 + t;
    int k = i >> 6, c = i & 63;
    WT2[c * 128 + k] = (_Float16)W2[i];
  } else {
    if (t < NBUK) gcur[t] = t * CAP;
    if (t == 0) { gctl[0] = 0; gctl[16] = 0; }
  }
}

// ---------------- gemm128 body (device fn, used by fused kernel) ----------------

__device__ __forceinline__ void gemm128_body(const float* __restrict__ x, const _Float16* __restrict__ WT,
                                             unsigned char* __restrict__ t8, int bid) {
  int wave = threadIdx.x >> 6, lane = threadIdx.x & 63;
  int col0 = wave * 32;
  int lr = lane & 15;
  int lk = (lane >> 4) * 8;
  hs8 bfrag[2][4];
#pragma unroll
  for (int n = 0; n < 2; n++)
#pragma unroll
    for (int ks = 0; ks < 4; ks++)
      bfrag[n][ks] = *(const hs8*)&WT[(size_t)(col0 + n * 16 + lr) * 128 + ks * 32 + lk];
  int row0 = bid * 64;
#pragma unroll 1
  for (int mt = 0; mt < 4; mt++) {
    int r0 = row0 + mt * 16;
    if (r0 >= NN) return;
    const float* xr = x + (size_t)(r0 + lr) * 128 + lk;
    f32x4 acc[2] = {{0.f, 0.f, 0.f, 0.f}, {0.f, 0.f, 0.f, 0.f}};
#pragma unroll
    for (int ks = 0; ks < 4; ks++) {
      float4 a0 = *(const float4*)&xr[ks * 32];
      float4 a1 = *(const float4*)&xr[ks * 32 + 4];
      hs8 af;
      af[0] = (_Float16)a0.x; af[1] = (_Float16)a0.y;
      af[2] = (_Float16)a0.z; af[3] = (_Float16)a0.w;
      af[4] = (_Float16)a1.x; af[5] = (_Float16)a1.y;
      af[6] = (_Float16)a1.z; af[7] = (_Float16)a1.w;
      acc[0] = MFMA16H(af, bfrag[0][ks], acc[0]);
      acc[1] = MFMA16H(af, bfrag[1][ks], acc[1]);
    }
    int rbase = r0 + (lane >> 4) * 4;
#pragma unroll
    for (int n = 0; n < 2; n++)
#pragma unroll
      for (int r = 0; r < 4; r++) {
        uint e = (uint)__builtin_amdgcn_cvt_pk_fp8_f32(acc[n][r], acc[n][r], 0, false);
        t8[(size_t)(rbase + r) * 128 + col0 + n * 16 + lr] = (unsigned char)(e & 0xffu);
      }
  }
}

// ---------------- fused: edge bucketing (blocks < nbB) + gemm128 (rest) ----------------
// single-atomic-pass binning: pass-1 atomicAdd returns local rank (packed rank<<17|row)

__global__ __launch_bounds__(256) void k_fused1(const int* __restrict__ row, const int* __restrict__ col,
                                                int* __restrict__ gcur, uint* __restrict__ pr_pack,
                                                const float* __restrict__ x, const _Float16* __restrict__ WT,
                                                unsigned char* __restrict__ t8, int nbB) {
  if ((int)blockIdx.x >= nbB) {
    gemm128_body(x, WT, t8, (int)blockIdx.x - nbB);
    return;
  }
  __shared__ int cnt[NBUK];
  int t = threadIdx.x;
  for (int i = t; i < NBUK; i += 256) cnt[i] = 0;
  __syncthreads();
  int e0 = blockIdx.x * CHUNK;
  uint rr[EPT]; int cc[EPT];
#pragma unroll
  for (int i = 0; i < EPT; i++) {
    int e = e0 + t + i * 256;
    bool ok = e < NE;
    cc[i] = ok ? col[e] : -1;
    rr[i] = ok ? (uint)row[e] : 0u;
  }
#pragma unroll
  for (int i = 0; i < EPT; i++)
    if (cc[i] >= 0) {
      uint rank = (uint)atomicAdd(&cnt[cc[i] >> BSH], 1);
      rr[i] |= rank << 17;  // row fits 17 bits (NN<2^17), rank fits 14
    }
  __syncthreads();
  for (int i = t; i < NBUK; i += 256) {
    int c = cnt[i];
    cnt[i] = c ? atomicAdd(&gcur[i], c) : 0;  // cnt becomes this block's base
  }
  __syncthreads();
#pragma unroll
  for (int i = 0; i < EPT; i++)
    if (cc[i] >= 0) {
      int p = cnt[cc[i] >> BSH] + (int)(rr[i] >> 17);
      pr_pack[p] = ((rr[i] & 0x1FFFFu) << BSH) | (uint)(cc[i] & (BSZ - 1));
    }
}

// ---------------- k_build: fused degree-count + CSR fill (grid barrier) ----------------
// Each block owns one bucket; caches its pr_pack slice in LDS. Phase 1: count,
// write deg/dinv. Barrier (all 196 blocks co-resident). Phase 2: local scan,
// atomic CSR base alloc, weighted fill. wcsr entry = (src_row, fp32 weight).

__global__ __launch_bounds__(256) void k_build(const uint* __restrict__ pr_pack, const int* __restrict__ gcur,
                                               int* __restrict__ deg, float* __restrict__ dinv,
                                               int* __restrict__ gctl, int* __restrict__ offs,
                                               uint2* __restrict__ wcsr) {
  __shared__ uint ep[CAP];
  __shared__ int dc[BSZ];
  __shared__ float dl[BSZ];
  __shared__ int loff[BSZ];
  __shared__ int cur[BSZ];
  __shared__ int tsum[256];
  __shared__ int sbase;
  int t = threadIdx.x, b = blockIdx.x;
  for (int i = t; i < BSZ; i += 256) dc[i] = 0;
  __syncthreads();
  int s = b * CAP;
  int n = min(gcur[b] - s, CAP);
  for (int i = t; i < n; i += 256) {
    uint v = pr_pack[s + i];
    ep[i] = v;
    atomicAdd(&dc[v & (BSZ - 1)], 1);
  }
  __syncthreads();
  int nb0 = b << BSH;
  for (int i = t; i < BSZ; i += 256) {
    int node = nb0 + i;
    if (node < NN) {
      int d = dc[i] + 1;
      deg[node] = d;
      float dv = rsqrtf((float)d);
      dinv[node] = dv;
      dl[i] = dv;
    } else {
      dl[i] = 0.f;
    }
  }
  // ---- grid barrier: all blocks' dinv visible before cross-bucket reads ----
  __threadfence();
  __syncthreads();
  if (t == 0) {
    __hip_atomic_fetch_add(&gctl[16], 1, __ATOMIC_ACQ_REL, __HIP_MEMORY_SCOPE_AGENT);
    while (__hip_atomic_load(&gctl[16], __ATOMIC_ACQUIRE, __HIP_MEMORY_SCOPE_AGENT) < NBUK) {}
  }
  __syncthreads();
  __threadfence();
  // ---- phase 2: local exclusive scan of deg (2 nodes/thread) ----
  int i0 = 2 * t, i1 = i0 + 1;
  int n0 = nb0 + i0, n1 = nb0 + i1;
  int d0 = (n0 < NN) ? dc[i0] + 1 : 0;
  int d1 = (n1 < NN) ? dc[i1] + 1 : 0;
  int v = d0 + d1;
  tsum[t] = v;
  __syncthreads();
  for (int d = 1; d < 256; d <<= 1) {
    int tmp = (t >= d) ? tsum[t - d] : 0;
    __syncthreads();
    tsum[t] += tmp;
    __syncthreads();
  }
  if (t == 255) sbase = atomicAdd(&gctl[0], tsum[255]);
  __syncthreads();
  int base = sbase + tsum[t] - v;
  loff[i0] = base;
  loff[i1] = base + d0;
  cur[i0] = 1;  // slot 0 = self loop
  cur[i1] = 1;
  if (n0 < NN) {
    offs[n0] = base;
    wcsr[base] = make_uint2((uint)n0, __float_as_uint(dl[i0] * dl[i0]));
  }
  if (n1 < NN) {
    offs[n1] = base + d0;
    wcsr[base + d0] = make_uint2((uint)n1, __float_as_uint(dl[i1] * dl[i1]));
  }
  __syncthreads();
  for (int i = t; i < n; i += 256) {
    uint prk = ep[i];
    int li = (int)(prk & (BSZ - 1));
    uint r = prk >> BSH;
    int p = atomicAdd(&cur[li], 1);
    uint dru = __hip_atomic_load((const uint*)&dinv[r], __ATOMIC_RELAXED, __HIP_MEMORY_SCOPE_AGENT);
    wcsr[loff[li] + p] = make_uint2(r, __float_as_uint(__uint_as_float(dru) * dl[li]));
  }
}

// ---------------- gemm64: t2[N,64](fp16) = h[N,128](fp16) @ W2 ----------------

__global__ __launch_bounds__(256) void k_gemm64(const _Float16* __restrict__ h, const _Float16* __restrict__ WT,
                                                _Float16* __restrict__ t2) {
  int wave = threadIdx.x >> 6, lane = threadIdx.x & 63;
  int col0 = wave * 16;
  int lr = lane & 15;
  int lk = (lane >> 4) * 8;
  hs8 bfrag[4];
#pragma unroll
  for (int ks = 0; ks < 4; ks++)
    bfrag[ks] = *(const hs8*)&WT[(size_t)(col0 + lr) * 128 + ks * 32 + lk];
  int row0 = blockIdx.x * 64;
#pragma unroll 1
  for (int mt = 0; mt < 4; mt++) {
    int r0 = row0 + mt * 16;
    if (r0 >= NN) return;
    const _Float16* hr = h + (size_t)(r0 + lr) * 128 + lk;
    f32x4 acc = {0.f, 0.f, 0.f, 0.f};
#pragma unroll
    for (int ks = 0; ks < 4; ks++) {
      hs8 af = *(const hs8*)&hr[ks * 32];
      acc = MFMA16H(af, bfrag[ks], acc);
    }
    int rbase = r0 + (lane >> 4) * 4;
#pragma unroll
    for (int r = 0; r < 4; r++)
      t2[(size_t)(rbase + r) * 64 + col0 + lr] = (_Float16)acc[r];
  }
}

// ---------------- aggregation (2 nodes/wave, 1-deep prefetch — round-10 proven form) ----------------

// layer 1: fp8 rows (128 B). half (32 lanes) per node; 2 subgroups of 16 per half.
__global__ __launch_bounds__(256) void k_agg128(const unsigned char* __restrict__ t8, const int* __restrict__ offs,
                                                const int* __restrict__ deg, const uint2* __restrict__ wcsr,
                                                const float* __restrict__ bias, _Float16* __restrict__ out) {
  int wave = threadIdx.x >> 6, lane = threadIdx.x & 63;
  int half = lane >> 5;          // 0: node A, 1: node B
  int sub = (lane >> 4) & 1;     // edge parity within half
  int f = lane & 15;             // feature lane (8 fp8 feats)
  int node = blockIdx.x * 8 + wave * 2 + half;
  int beg = offs[node];
  int d = deg[node];             // includes self-loop
  const char* tb = (const char*)t8;
  float acc[8] = {};
  int trips = (d + 1) >> 1;
  uint2 e = (sub < d) ? wcsr[beg + sub] : make_uint2(0u, 0u);
#pragma unroll 1
  for (int k = 0; k < trips; k++) {
    int ns = (k + 1) * 2 + sub;
    uint2 en = (ns < d) ? wcsr[beg + ns] : make_uint2(0u, 0u);
    float s = __uint_as_float(e.y);  // 0 for padded slots
    uint2 u = *(const uint2*)(tb + (((size_t)e.x) << 7) + (f << 3));
    f32x2 p0 = __builtin_amdgcn_cvt_pk_f32_fp8(u.x, false);
    f32x2 p1 = __builtin_amdgcn_cvt_pk_f32_fp8(u.x, true);
    f32x2 p2 = __builtin_amdgcn_cvt_pk_f32_fp8(u.y, false);
    f32x2 p3 = __builtin_amdgcn_cvt_pk_f32_fp8(u.y, true);
    acc[0] = fmaf(p0[0], s, acc[0]);
    acc[1] = fmaf(p0[1], s, acc[1]);
    acc[2] = fmaf(p1[0], s, acc[2]);
    acc[3] = fmaf(p1[1], s, acc[3]);
    acc[4] = fmaf(p2[0], s, acc[4]);
    acc[5] = fmaf(p2[1], s, acc[5]);
    acc[6] = fmaf(p3[0], s, acc[6]);
    acc[7] = fmaf(p3[1], s, acc[7]);
    e = en;
  }
#pragma unroll
  for (int j = 0; j < 8; j++) acc[j] += __shfl_xor(acc[j], 16);
  if (sub == 0) {
    float4 b0 = *(const float4*)&bias[f * 8];
    float4 b1 = *(const float4*)&bias[f * 8 + 4];
    h8u st;
    st.h[0] = (_Float16)fmaxf(acc[0] + b0.x, 0.f);
    st.h[1] = (_Float16)fmaxf(acc[1] + b0.y, 0.f);
    st.h[2] = (_Float16)fmaxf(acc[2] + b0.z, 0.f);
    st.h[3] = (_Float16)fmaxf(acc[3] + b0.w, 0.f);
    st.h[4] = (_Float16)fmaxf(acc[4] + b1.x, 0.f);
    st.h[5] = (_Float16)fmaxf(acc[5] + b1.y, 0.f);
    st.h[6] = (_Float16)fmaxf(acc[6] + b1.z, 0.f);
    st.h[7] = (_Float16)fmaxf(acc[7] + b1.w, 0.f);
    *(uint4*)&out[(size_t)node * 128 + f * 8] = st.q;
  }
}

// layer 2: fp16 rows (128 B). half (32 lanes) per node; 4 subgroups of 8 per half.
__global__ __launch_bounds__(256) void k_agg64(const _Float16* __restrict__ t, const int* __restrict__ offs,
                                               const int* __restrict__ deg, const uint2* __restrict__ wcsr,
                                               const float* __restrict__ bias, float* __restrict__ out) {
  int wave = threadIdx.x >> 6, lane = threadIdx.x & 63;
  int half = lane >> 5;
  int sub = (lane >> 3) & 3;     // edge slot within half
  int f8 = lane & 7;             // feature lane (8 fp16 feats)
  int node = blockIdx.x * 8 + wave * 2 + half;
  int beg = offs[node];
  int d = deg[node];
  const char* tb = (const char*)t;
  float acc[8] = {};
  int trips = (d + 3) >> 2;
  uint2 e = (sub < d) ? wcsr[beg + sub] : make_uint2(0u, 0u);
#pragma unroll 1
  for (int k = 0; k < trips; k++) {
    int ns = (k + 1) * 4 + sub;
    uint2 en = (ns < d) ? wcsr[beg + ns] : make_uint2(0u, 0u);
    float s = __uint_as_float(e.y);
    h8u u;
    u.q = *(const uint4*)(tb + (((size_t)e.x) << 7) + (f8 << 4));
    acc[0] = fmaf((float)u.h[0], s, acc[0]);
    acc[1] = fmaf((float)u.h[1], s, acc[1]);
    acc[2] = fmaf((float)u.h[2], s, acc[2]);
    acc[3] = fmaf((float)u.h[3], s, acc[3]);
    acc[4] = fmaf((float)u.h[4], s, acc[4]);
    acc[5] = fmaf((float)u.h[5], s, acc[5]);
    acc[6] = fmaf((float)u.h[6], s, acc[6]);
    acc[7] = fmaf((float)u.h[7], s, acc[7]);
    e = en;
  }
#pragma unroll
  for (int j = 0; j < 8; j++) {
    acc[j] += __shfl_xor(acc[j], 8);
    acc[j] += __shfl_xor(acc[j], 16);
  }
  if (sub == 0) {
    float4 b0 = *(const float4*)&bias[f8 * 8];
    float4 b1 = *(const float4*)&bias[f8 * 8 + 4];
    float4 o0 = make_float4(acc[0] + b0.x, acc[1] + b0.y, acc[2] + b0.z, acc[3] + b0.w);
    float4 o1 = make_float4(acc[4] + b1.x, acc[5] + b1.y, acc[6] + b1.z, acc[7] + b1.w);
    *(float4*)&out[(size_t)node * 64 + f8 * 8] = o0;
    *(float4*)&out[(size_t)node * 64 + f8 * 8 + 4] = o1;
  }
}

// ---------------- host ----------------

extern "C" void kernel_launch(void* const* d_in, const int* in_sizes, int n_in,
                              void* d_out, int out_size, void* d_ws, size_t ws_size,
                              hipStream_t stream) {
  const float* x  = (const float*)d_in[0];
  const int*   ei = (const int*)d_in[1];
  const float* W1 = (const float*)d_in[2];
  const float* b1 = (const float*)d_in[3];
  const float* W2 = (const float*)d_in[4];
  const float* b2 = (const float*)d_in[5];
  float* out = (float*)d_out;

  char* p = (char*)d_ws;
  int* deg       = (int*)p;      p += alignup((size_t)NN * 4);
  int* gcur      = (int*)p;      p += alignup((size_t)NBUK * 4);
  int* offs      = (int*)p;      p += alignup((size_t)NN * 4);
  int* gctl      = (int*)p;      p += alignup(256);
  float* dinv    = (float*)p;    p += alignup((size_t)NN * 4);
  uint2* wcsr    = (uint2*)p;    p += alignup((size_t)(NE + NN + 64) * 8);
  _Float16* WT1  = (_Float16*)p; p += alignup(128 * 128 * 2);
  _Float16* WT2  = (_Float16*)p; p += alignup(64 * 128 * 2);
  unsigned char* t8 = (unsigned char*)p; p += alignup((size_t)NN * 128);
  _Float16* t2   = (_Float16*)p; p += alignup((size_t)NN * 64 * 2);
  _Float16* h1   = (_Float16*)p; p += alignup((size_t)NN * 128 * 2);
  // packed pair buffer aliases t2 (dead until k_gemm64 writes it); 6.4 MB <= 12.8 MB
  uint* pr_pack  = (uint*)t2;
  (void)ws_size; (void)in_sizes; (void)n_in; (void)out_size;

  const int* row = ei;
  const int* col = ei + NE;

  int nbB = (NE + CHUNK - 1) / CHUNK;
  int nbG = (NN + 63) / 64;
  int nbA = NN / 8;

  k_prep0<<<97, 256, 0, stream>>>(gcur, gctl, W1, WT1, W2, WT2);
  k_fused1<<<nbB + nbG, 256, 0, stream>>>(row, col, gcur, pr_pack, x, WT1, t8, nbB);
  k_build<<<NBUK, 256, 0, stream>>>(pr_pack, gcur, deg, dinv, gctl, offs, wcsr);
  k_agg128<<<nbA, 256, 0, stream>>>(t8, offs, deg, wcsr, b1, h1);
  k_gemm64<<<nbG, 256, 0, stream>>>(h1, WT2, t2);
  k_agg64<<<nbA, 256, 0, stream>>>(t2, offs, deg, wcsr, b2, out);
}

// Round 13
// 199.455 us; speedup vs baseline: 1.0452x; 1.0452x over previous
//
#include <hip/hip_runtime.h>

#define NN 100000
#define NE 1600000

// bucketed counting sort params: 512 nodes per bucket
#define BSH 9
#define BSZ 512
#define NBUK 196          // ceil(NN / BSZ)
#define CAP 12288         // per-bucket pair capacity (mean 8163, huge margin)
#define CHUNK 4096        // edges per block in bucket phase
#define EPT 16            // edges per thread (CHUNK/256)

typedef _Float16 hs8 __attribute__((ext_vector_type(8)));
typedef float f32x4 __attribute__((ext_vector_type(4)));
typedef float f32x2 __attribute__((ext_vector_type(2)));
#define MFMA16H(a, b, c) __builtin_amdgcn_mfma_f32_16x16x32_f16(a, b, c, 0, 0, 0)

static inline size_t alignup(size_t x) { return (x + 255) & ~(size_t)255; }

union h8u { uint4 q; _Float16 h[8]; };

// ---------------- fused0: edge bucketing + W converts + t8 dummy-row zero ----------------
// gcur[b] counts entries per bucket (starts 0 via memset); slot = b*CAP + base + rank.

__global__ __launch_bounds__(256) void k_fused0(const int* __restrict__ row, const int* __restrict__ col,
                                                int* __restrict__ gcur, uint* __restrict__ pr_pack,
                                                const float* __restrict__ W1, _Float16* __restrict__ WT1,
                                                const float* __restrict__ W2, _Float16* __restrict__ WT2,
                                                unsigned char* __restrict__ t8, int nbB) {
  int b = (int)blockIdx.x, t = threadIdx.x;
  if (b >= nbB) {
    int w = b - nbB;
    if (w < 64) {          // W1: [128,128] -> WT1[c][k]
      int i = w * 256 + t;
      int k = i >> 7, c = i & 127;
      WT1[c * 128 + k] = (_Float16)W1[i];
    } else if (w < 96) {   // W2: [128,64] -> WT2[c][k]
      int i = (w - 64) * 256 + t;
      int k = i >> 6, c = i & 63;
      WT2[c * 128 + k] = (_Float16)W2[i];
    } else {               // zero dummy row t8[NN]
      if (t < 32) ((uint*)(t8 + (size_t)NN * 128))[t] = 0u;
    }
    return;
  }
  __shared__ int cnt[NBUK];
  for (int i = t; i < NBUK; i += 256) cnt[i] = 0;
  __syncthreads();
  int e0 = b * CHUNK;
  uint rr[EPT]; int cc[EPT];
#pragma unroll
  for (int i = 0; i < EPT; i++) {
    int e = e0 + t + i * 256;
    bool ok = e < NE;
    cc[i] = ok ? col[e] : -1;
    rr[i] = ok ? (uint)row[e] : 0u;
  }
#pragma unroll
  for (int i = 0; i < EPT; i++)
    if (cc[i] >= 0) {
      uint rank = (uint)atomicAdd(&cnt[cc[i] >> BSH], 1);
      rr[i] |= rank << 17;  // row fits 17 bits (NN<2^17), rank fits 14
    }
  __syncthreads();
  for (int i = t; i < NBUK; i += 256) {
    int c = cnt[i];
    cnt[i] = c ? (i * CAP + atomicAdd(&gcur[i], c)) : 0;  // block's global base
  }
  __syncthreads();
#pragma unroll
  for (int i = 0; i < EPT; i++)
    if (cc[i] >= 0) {
      int p = cnt[cc[i] >> BSH] + (int)(rr[i] >> 17);
      pr_pack[p] = ((rr[i] & 0x1FFFFu) << BSH) | (uint)(cc[i] & (BSZ - 1));
    }
}

// ---------------- bdeg: per-bucket degree count (+1 self loop) + dinv ----------------

__global__ __launch_bounds__(256) void k_bdeg(const uint* __restrict__ pr_pack, const int* __restrict__ gcur,
                                              int* __restrict__ deg, float* __restrict__ dinv) {
  __shared__ int dc[BSZ];
  int t = threadIdx.x, b = blockIdx.x;
  for (int i = t; i < BSZ; i += 256) dc[i] = 0;
  __syncthreads();
  int s = b * CAP;
  int n = min(gcur[b], CAP);
  for (int i = t; i < n; i += 256) atomicAdd(&dc[pr_pack[s + i] & (BSZ - 1)], 1);
  __syncthreads();
  int nb0 = b << BSH;
  for (int i = t; i < BSZ; i += 256) {
    int node = nb0 + i;
    if (node < NN) {
      int d = dc[i] + 1;
      deg[node] = d;
      dinv[node] = rsqrtf((float)d);
    }
  }
}

// ---------------- gemm128 body: t8[r] = fp8( dinv[r] * (x[r] @ W1) ) ----------------

__device__ __forceinline__ void gemm128_body(const float* __restrict__ x, const _Float16* __restrict__ WT,
                                             const float* __restrict__ dinv, unsigned char* __restrict__ t8,
                                             int bid) {
  int wave = threadIdx.x >> 6, lane = threadIdx.x & 63;
  int col0 = wave * 32;
  int lr = lane & 15;
  int lk = (lane >> 4) * 8;
  hs8 bfrag[2][4];
#pragma unroll
  for (int n = 0; n < 2; n++)
#pragma unroll
    for (int ks = 0; ks < 4; ks++)
      bfrag[n][ks] = *(const hs8*)&WT[(size_t)(col0 + n * 16 + lr) * 128 + ks * 32 + lk];
  int row0 = bid * 64;
#pragma unroll 1
  for (int mt = 0; mt < 4; mt++) {
    int r0 = row0 + mt * 16;
    if (r0 >= NN) return;
    const float* xr = x + (size_t)(r0 + lr) * 128 + lk;
    f32x4 acc[2] = {{0.f, 0.f, 0.f, 0.f}, {0.f, 0.f, 0.f, 0.f}};
#pragma unroll
    for (int ks = 0; ks < 4; ks++) {
      float4 a0 = *(const float4*)&xr[ks * 32];
      float4 a1 = *(const float4*)&xr[ks * 32 + 4];
      hs8 af;
      af[0] = (_Float16)a0.x; af[1] = (_Float16)a0.y;
      af[2] = (_Float16)a0.z; af[3] = (_Float16)a0.w;
      af[4] = (_Float16)a1.x; af[5] = (_Float16)a1.y;
      af[6] = (_Float16)a1.z; af[7] = (_Float16)a1.w;
      acc[0] = MFMA16H(af, bfrag[0][ks], acc[0]);
      acc[1] = MFMA16H(af, bfrag[1][ks], acc[1]);
    }
    int rbase = r0 + (lane >> 4) * 4;
#pragma unroll
    for (int r = 0; r < 4; r++) {
      float dv = dinv[rbase + r];
#pragma unroll
      for (int n = 0; n < 2; n++) {
        float v = acc[n][r] * dv;
        uint e = (uint)__builtin_amdgcn_cvt_pk_fp8_f32(v, v, 0, false);
        t8[(size_t)(rbase + r) * 128 + col0 + n * 16 + lr] = (unsigned char)(e & 0xffu);
      }
    }
  }
}

// ---------------- fused2: bfill (blocks < NBUK) + gemm128 (rest) ----------------
// bfill: local scan of deg -> offs, atomic CSR base alloc, plain-index fill.

__global__ __launch_bounds__(256) void k_fused2(const uint* __restrict__ pr_pack, const int* __restrict__ gcur,
                                                const int* __restrict__ deg, int* __restrict__ gctl,
                                                int* __restrict__ offs, int* __restrict__ csr,
                                                const float* __restrict__ x, const _Float16* __restrict__ WT,
                                                const float* __restrict__ dinv, unsigned char* __restrict__ t8) {
  if ((int)blockIdx.x >= NBUK) {
    gemm128_body(x, WT, dinv, t8, (int)blockIdx.x - NBUK);
    return;
  }
  __shared__ int loff[BSZ];
  __shared__ int cur[BSZ];
  __shared__ int tsum[256];
  __shared__ int sbase;
  int t = threadIdx.x, b = blockIdx.x;
  int nb0 = b << BSH;
  int i0 = 2 * t, i1 = i0 + 1;
  int n0 = nb0 + i0, n1 = nb0 + i1;
  int d0 = (n0 < NN) ? deg[n0] : 0;
  int d1 = (n1 < NN) ? deg[n1] : 0;
  int v = d0 + d1;
  tsum[t] = v;
  __syncthreads();
  for (int d = 1; d < 256; d <<= 1) {
    int tmp = (t >= d) ? tsum[t - d] : 0;
    __syncthreads();
    tsum[t] += tmp;
    __syncthreads();
  }
  if (t == 255) sbase = atomicAdd(&gctl[0], tsum[255]);
  __syncthreads();
  int base = sbase + tsum[t] - v;  // bucket CSR base + exclusive local offset
  loff[i0] = base;
  loff[i1] = base + d0;
  cur[i0] = 1;  // slot 0 = self loop
  cur[i1] = 1;
  if (n0 < NN) { offs[n0] = base;      csr[base] = n0; }
  if (n1 < NN) { offs[n1] = base + d0; csr[base + d0] = n1; }
  __syncthreads();
  int s = b * CAP;
  int n = min(gcur[b], CAP);
  for (int i = t; i < n; i += 256) {
    uint prk = pr_pack[s + i];
    int li = (int)(prk & (BSZ - 1));
    int p = atomicAdd(&cur[li], 1);
    csr[loff[li] + p] = (int)(prk >> BSH);
  }
}

// ---------------- gemm64: t2[r] = fp16( dinv[r] * (h[r] @ W2) ); block nbG zeroes t2[NN] ----------------

__global__ __launch_bounds__(256) void k_gemm64(const _Float16* __restrict__ h, const _Float16* __restrict__ WT,
                                                const float* __restrict__ dinv, _Float16* __restrict__ t2,
                                                int nbG) {
  if ((int)blockIdx.x >= nbG) {
    if (threadIdx.x < 32) ((uint*)(t2 + (size_t)NN * 64))[threadIdx.x] = 0u;
    return;
  }
  int wave = threadIdx.x >> 6, lane = threadIdx.x & 63;
  int col0 = wave * 16;
  int lr = lane & 15;
  int lk = (lane >> 4) * 8;
  hs8 bfrag[4];
#pragma unroll
  for (int ks = 0; ks < 4; ks++)
    bfrag[ks] = *(const hs8*)&WT[(size_t)(col0 + lr) * 128 + ks * 32 + lk];
  int row0 = blockIdx.x * 64;
#pragma unroll 1
  for (int mt = 0; mt < 4; mt++) {
    int r0 = row0 + mt * 16;
    if (r0 >= NN) return;
    const _Float16* hr = h + (size_t)(r0 + lr) * 128 + lk;
    f32x4 acc = {0.f, 0.f, 0.f, 0.f};
#pragma unroll
    for (int ks = 0; ks < 4; ks++) {
      hs8 af = *(const hs8*)&hr[ks * 32];
      acc = MFMA16H(af, bfrag[ks], acc);
    }
    int rbase = r0 + (lane >> 4) * 4;
#pragma unroll
    for (int r = 0; r < 4; r++)
      t2[(size_t)(rbase + r) * 64 + col0 + lr] = (_Float16)(acc[r] * dinv[rbase + r]);
  }
}

// ---------------- aggregation (2 nodes/wave, plain-sum CSR, dinv at epilogue) ----------------

// layer 1: fp8 rows (128 B). half (32 lanes) per node; 2 subgroups of 16 per half.
__global__ __launch_bounds__(256) void k_agg128(const unsigned char* __restrict__ t8, const int* __restrict__ offs,
                                                const int* __restrict__ deg, const int* __restrict__ csr,
                                                const float* __restrict__ dinv, const float* __restrict__ bias,
                                                _Float16* __restrict__ out) {
  int wave = threadIdx.x >> 6, lane = threadIdx.x & 63;
  int half = lane >> 5;          // 0: node A, 1: node B
  int sub = (lane >> 4) & 1;     // edge parity within half
  int f = lane & 15;             // feature lane (8 fp8 feats)
  int node = blockIdx.x * 8 + wave * 2 + half;
  int beg = offs[node];
  int d = deg[node];             // includes self-loop
  const char* tb = (const char*)t8;
  float acc[8] = {};
  int trips = (d + 1) >> 1;
  int r = (sub < d) ? csr[beg + sub] : NN;   // NN = zero dummy row
#pragma unroll 1
  for (int k = 0; k < trips; k++) {
    int ns = (k + 1) * 2 + sub;
    int rn = (ns < d) ? csr[beg + ns] : NN;
    uint2 u = *(const uint2*)(tb + (((size_t)(uint)r) << 7) + (f << 3));
    f32x2 p0 = __builtin_amdgcn_cvt_pk_f32_fp8(u.x, false);
    f32x2 p1 = __builtin_amdgcn_cvt_pk_f32_fp8(u.x, true);
    f32x2 p2 = __builtin_amdgcn_cvt_pk_f32_fp8(u.y, false);
    f32x2 p3 = __builtin_amdgcn_cvt_pk_f32_fp8(u.y, true);
    acc[0] += p0[0]; acc[1] += p0[1];
    acc[2] += p1[0]; acc[3] += p1[1];
    acc[4] += p2[0]; acc[5] += p2[1];
    acc[6] += p3[0]; acc[7] += p3[1];
    r = rn;
  }
#pragma unroll
  for (int j = 0; j < 8; j++) acc[j] += __shfl_xor(acc[j], 16);
  if (sub == 0) {
    float dv = dinv[node];
    float4 b0 = *(const float4*)&bias[f * 8];
    float4 b1 = *(const float4*)&bias[f * 8 + 4];
    h8u st;
    st.h[0] = (_Float16)fmaxf(fmaf(acc[0], dv, b0.x), 0.f);
    st.h[1] = (_Float16)fmaxf(fmaf(acc[1], dv, b0.y), 0.f);
    st.h[2] = (_Float16)fmaxf(fmaf(acc[2], dv, b0.z), 0.f);
    st.h[3] = (_Float16)fmaxf(fmaf(acc[3], dv, b0.w), 0.f);
    st.h[4] = (_Float16)fmaxf(fmaf(acc[4], dv, b1.x), 0.f);
    st.h[5] = (_Float16)fmaxf(fmaf(acc[5], dv, b1.y), 0.f);
    st.h[6] = (_Float16)fmaxf(fmaf(acc[6], dv, b1.z), 0.f);
    st.h[7] = (_Float16)fmaxf(fmaf(acc[7], dv, b1.w), 0.f);
    *(uint4*)&out[(size_t)node * 128 + f * 8] = st.q;
  }
}

// layer 2: fp16 rows (128 B). half (32 lanes) per node; 4 subgroups of 8 per half.
__global__ __launch_bounds__(256) void k_agg64(const _Float16* __restrict__ t, const int* __restrict__ offs,
                                               const int* __restrict__ deg, const int* __restrict__ csr,
                                               const float* __restrict__ dinv, const float* __restrict__ bias,
                                               float* __restrict__ out) {
  int wave = threadIdx.x >> 6, lane = threadIdx.x & 63;
  int half = lane >> 5;
  int sub = (lane >> 3) & 3;     // edge slot within half
  int f8 = lane & 7;             // feature lane (8 fp16 feats)
  int node = blockIdx.x * 8 + wave * 2 + half;
  int beg = offs[node];
  int d = deg[node];
  const char* tb = (const char*)t;
  float acc[8] = {};
  int trips = (d + 3) >> 2;
  int r = (sub < d) ? csr[beg + sub] : NN;
#pragma unroll 1
  for (int k = 0; k < trips; k++) {
    int ns = (k + 1) * 4 + sub;
    int rn = (ns < d) ? csr[beg + ns] : NN;
    h8u u;
    u.q = *(const uint4*)(tb + (((size_t)(uint)r) << 7) + (f8 << 4));
    acc[0] += (float)u.h[0];
    acc[1] += (float)u.h[1];
    acc[2] += (float)u.h[2];
    acc[3] += (float)u.h[3];
    acc[4] += (float)u.h[4];
    acc[5] += (float)u.h[5];
    acc[6] += (float)u.h[6];
    acc[7] += (float)u.h[7];
    r = rn;
  }
#pragma unroll
  for (int j = 0; j < 8; j++) {
    acc[j] += __shfl_xor(acc[j], 8);
    acc[j] += __shfl_xor(acc[j], 16);
  }
  if (sub == 0) {
    float dv = dinv[node];
    float4 b0 = *(const float4*)&bias[f8 * 8];
    float4 b1 = *(const float4*)&bias[f8 * 8 + 4];
    float4 o0 = make_float4(fmaf(acc[0], dv, b0.x), fmaf(acc[1], dv, b0.y),
                            fmaf(acc[2], dv, b0.z), fmaf(acc[3], dv, b0.w));
    float4 o1 = make_float4(fmaf(acc[4], dv, b1.x), fmaf(acc[5], dv, b1.y),
                            fmaf(acc[6], dv, b1.z), fmaf(acc[7], dv, b1.w));
    *(float4*)&out[(size_t)node * 64 + f8 * 8] = o0;
    *(float4*)&out[(size_t)node * 64 + f8 * 8 + 4] = o1;
  }
}

// ---------------- host ----------------

extern "C" void kernel_launch(void* const* d_in, const int* in_sizes, int n_in,
                              void* d_out, int out_size, void* d_ws, size_t ws_size,
                              hipStream_t stream) {
  const float* x  = (const float*)d_in[0];
  const int*   ei = (const int*)d_in[1];
  const float* W1 = (const float*)d_in[2];
  const float* b1 = (const float*)d_in[3];
  const float* W2 = (const float*)d_in[4];
  const float* b2 = (const float*)d_in[5];
  float* out = (float*)d_out;

  char* p = (char*)d_ws;
  int* gcur      = (int*)p;      p += alignup((size_t)NBUK * 4);   // |
  int* gctl      = (int*)p;      p += alignup(256);                 // | one contiguous memset region
  int* deg       = (int*)p;      p += alignup((size_t)NN * 4);
  int* offs      = (int*)p;      p += alignup((size_t)NN * 4);
  float* dinv    = (float*)p;    p += alignup((size_t)NN * 4);
  int* csr       = (int*)p;      p += alignup((size_t)(NE + NN + 64) * 4);
  _Float16* WT1  = (_Float16*)p; p += alignup(128 * 128 * 2);
  _Float16* WT2  = (_Float16*)p; p += alignup(64 * 128 * 2);
  unsigned char* t8 = (unsigned char*)p; p += alignup((size_t)(NN + 1) * 128);
  _Float16* t2   = (_Float16*)p; p += alignup((size_t)(NN + 1) * 64 * 2);
  _Float16* h1   = (_Float16*)p; p += alignup((size_t)NN * 128 * 2);
  // packed pair buffer aliases t2 (dead after k_fused2; t2 written by k_gemm64); 6.4 MB <= 12.8 MB
  uint* pr_pack  = (uint*)t2;
  (void)ws_size; (void)in_sizes; (void)n_in; (void)out_size;

  const int* row = ei;
  const int* col = ei + NE;

  int nbB = (NE + CHUNK - 1) / CHUNK;
  int nbG = (NN + 63) / 64;
  int nbA = NN / 8;

  hipMemsetAsync(gcur, 0, alignup((size_t)NBUK * 4) + 256, stream);
  k_fused0<<<nbB + 97, 256, 0, stream>>>(row, col, gcur, pr_pack, W1, WT1, W2, WT2, t8, nbB);
  k_bdeg<<<NBUK, 256, 0, stream>>>(pr_pack, gcur, deg, dinv);
  k_fused2<<<NBUK + nbG, 256, 0, stream>>>(pr_pack, gcur, deg, gctl, offs, csr, x, WT1, dinv, t8);
  k_agg128<<<nbA, 256, 0, stream>>>(t8, offs, deg, csr, dinv, b1, h1);
  k_gemm64<<<nbG + 1, 256, 0, stream>>>(h1, WT2, dinv, t2, nbG);
  k_agg64<<<nbA, 256, 0, stream>>>(t2, offs, deg, csr, dinv, b2, out);
}

// Round 14
// 185.195 us; speedup vs baseline: 1.1257x; 1.0770x over previous
//
#include <hip/hip_runtime.h>

#define NN 100000
#define NE 1600000

// bucketed counting sort params: 512 nodes per bucket
#define BSH 9
#define BSZ 512
#define NBUK 196          // ceil(NN / BSZ)
#define CAP 12288         // per-bucket pair capacity (mean 8163, huge margin)
#define CHUNK 4096        // edges per block in bucket phase
#define EPT 16            // edges per thread (CHUNK/256)

typedef _Float16 hs8 __attribute__((ext_vector_type(8)));
typedef float f32x4 __attribute__((ext_vector_type(4)));
typedef float f32x2 __attribute__((ext_vector_type(2)));
#define MFMA16H(a, b, c) __builtin_amdgcn_mfma_f32_16x16x32_f16(a, b, c, 0, 0, 0)

static inline size_t alignup(size_t x) { return (x + 255) & ~(size_t)255; }

union h8u { uint4 q; _Float16 h[8]; };

// ---------------- k_bucket: edge binning (blocks < nbB) + W converts (rest) ----------------
// gcur[b] counts entries per bucket (memset 0); slot = b*CAP + base + rank.
// single-atomic-pass: pass-1 atomicAdd returns local rank (packed rank<<17|row)

__global__ __launch_bounds__(256) void k_bucket(const int* __restrict__ row, const int* __restrict__ col,
                                                int* __restrict__ gcur, uint* __restrict__ pr_pack,
                                                const float* __restrict__ W1, _Float16* __restrict__ WT1,
                                                const float* __restrict__ W2, _Float16* __restrict__ WT2,
                                                int nbB) {
  int b = (int)blockIdx.x, t = threadIdx.x;
  if (b >= nbB) {
    int w = b - nbB;
    if (w < 64) {          // W1: [128,128] -> WT1[c][k]
      int i = w * 256 + t;
      int k = i >> 7, c = i & 127;
      WT1[c * 128 + k] = (_Float16)W1[i];
    } else {               // W2: [128,64] -> WT2[c][k]
      int i = (w - 64) * 256 + t;
      int k = i >> 6, c = i & 63;
      WT2[c * 128 + k] = (_Float16)W2[i];
    }
    return;
  }
  __shared__ int cnt[NBUK];
  for (int i = t; i < NBUK; i += 256) cnt[i] = 0;
  __syncthreads();
  int e0 = b * CHUNK;
  uint rr[EPT]; int cc[EPT];
#pragma unroll
  for (int i = 0; i < EPT; i++) {
    int e = e0 + t + i * 256;
    bool ok = e < NE;
    cc[i] = ok ? col[e] : -1;
    rr[i] = ok ? (uint)row[e] : 0u;
  }
#pragma unroll
  for (int i = 0; i < EPT; i++)
    if (cc[i] >= 0) {
      uint rank = (uint)atomicAdd(&cnt[cc[i] >> BSH], 1);
      rr[i] |= rank << 17;  // row fits 17 bits (NN<2^17), rank fits 13
    }
  __syncthreads();
  for (int i = t; i < NBUK; i += 256) {
    int c = cnt[i];
    cnt[i] = c ? (i * CAP + atomicAdd(&gcur[i], c)) : 0;  // block's global base
  }
  __syncthreads();
#pragma unroll
  for (int i = 0; i < EPT; i++)
    if (cc[i] >= 0) {
      int p = cnt[cc[i] >> BSH] + (int)(rr[i] >> 17);
      pr_pack[p] = ((rr[i] & 0x1FFFFu) << BSH) | (uint)(cc[i] & (BSZ - 1));
    }
}

// ---------------- gemm128 body: t8[r] = fp8( x[r] @ W1 ) ----------------

__device__ __forceinline__ void gemm128_body(const float* __restrict__ x, const _Float16* __restrict__ WT,
                                             unsigned char* __restrict__ t8, int bid) {
  int wave = threadIdx.x >> 6, lane = threadIdx.x & 63;
  int col0 = wave * 32;
  int lr = lane & 15;
  int lk = (lane >> 4) * 8;
  hs8 bfrag[2][4];
#pragma unroll
  for (int n = 0; n < 2; n++)
#pragma unroll
    for (int ks = 0; ks < 4; ks++)
      bfrag[n][ks] = *(const hs8*)&WT[(size_t)(col0 + n * 16 + lr) * 128 + ks * 32 + lk];
  int row0 = bid * 64;
#pragma unroll 1
  for (int mt = 0; mt < 4; mt++) {
    int r0 = row0 + mt * 16;
    if (r0 >= NN) return;
    const float* xr = x + (size_t)(r0 + lr) * 128 + lk;
    f32x4 acc[2] = {{0.f, 0.f, 0.f, 0.f}, {0.f, 0.f, 0.f, 0.f}};
#pragma unroll
    for (int ks = 0; ks < 4; ks++) {
      float4 a0 = *(const float4*)&xr[ks * 32];
      float4 a1 = *(const float4*)&xr[ks * 32 + 4];
      hs8 af;
      af[0] = (_Float16)a0.x; af[1] = (_Float16)a0.y;
      af[2] = (_Float16)a0.z; af[3] = (_Float16)a0.w;
      af[4] = (_Float16)a1.x; af[5] = (_Float16)a1.y;
      af[6] = (_Float16)a1.z; af[7] = (_Float16)a1.w;
      acc[0] = MFMA16H(af, bfrag[0][ks], acc[0]);
      acc[1] = MFMA16H(af, bfrag[1][ks], acc[1]);
    }
    int rbase = r0 + (lane >> 4) * 4;
#pragma unroll
    for (int n = 0; n < 2; n++)
#pragma unroll
      for (int r = 0; r < 4; r++) {
        uint e = (uint)__builtin_amdgcn_cvt_pk_fp8_f32(acc[n][r], acc[n][r], 0, false);
        t8[(size_t)(rbase + r) * 128 + col0 + n * 16 + lr] = (unsigned char)(e & 0xffu);
      }
  }
}

// ---------------- k_fbg: bdeg (blocks < NBUK, underutilized) + gemm128 (rest) ----------------

__global__ __launch_bounds__(256) void k_fbg(const uint* __restrict__ pr_pack, const int* __restrict__ gcur,
                                             int* __restrict__ deg, float* __restrict__ dinv,
                                             const float* __restrict__ x, const _Float16* __restrict__ WT,
                                             unsigned char* __restrict__ t8) {
  if ((int)blockIdx.x >= NBUK) {
    gemm128_body(x, WT, t8, (int)blockIdx.x - NBUK);
    return;
  }
  __shared__ int dc[BSZ];
  int t = threadIdx.x, b = blockIdx.x;
  for (int i = t; i < BSZ; i += 256) dc[i] = 0;
  __syncthreads();
  int s = b * CAP;
  int n = min(gcur[b], CAP);
  for (int i = t; i < n; i += 256) atomicAdd(&dc[pr_pack[s + i] & (BSZ - 1)], 1);
  __syncthreads();
  int nb0 = b << BSH;
  for (int i = t; i < BSZ; i += 256) {
    int node = nb0 + i;
    if (node < NN) {
      int d = dc[i] + 1;
      deg[node] = d;
      dinv[node] = rsqrtf((float)d);
    }
  }
}

// ---------------- k_bfill: local scan + atomic CSR base alloc + weighted fill ----------------
// wcsr entry = (src_row, fp32 weight); slot 0 of each node = self loop

__global__ __launch_bounds__(256) void k_bfill(const uint* __restrict__ pr_pack, const int* __restrict__ gcur,
                                               const int* __restrict__ deg, const float* __restrict__ dinv,
                                               int* __restrict__ gctl, int* __restrict__ offs,
                                               uint2* __restrict__ wcsr) {
  __shared__ int loff[BSZ];
  __shared__ int cur[BSZ];
  __shared__ float dl[BSZ];
  __shared__ int tsum[256];
  __shared__ int sbase;
  int t = threadIdx.x, b = blockIdx.x;
  int nb0 = b << BSH;
  int i0 = 2 * t, i1 = i0 + 1;
  int n0 = nb0 + i0, n1 = nb0 + i1;
  int d0 = (n0 < NN) ? deg[n0] : 0;
  int d1 = (n1 < NN) ? deg[n1] : 0;
  int v = d0 + d1;
  tsum[t] = v;
  __syncthreads();
  for (int d = 1; d < 256; d <<= 1) {
    int tmp = (t >= d) ? tsum[t - d] : 0;
    __syncthreads();
    tsum[t] += tmp;
    __syncthreads();
  }
  if (t == 255) sbase = atomicAdd(&gctl[0], tsum[255]);
  __syncthreads();
  int base = sbase + tsum[t] - v;  // bucket CSR base + exclusive local offset
  float dv0 = (n0 < NN) ? dinv[n0] : 0.f;
  float dv1 = (n1 < NN) ? dinv[n1] : 0.f;
  loff[i0] = base;
  loff[i1] = base + d0;
  dl[i0] = dv0;
  dl[i1] = dv1;
  cur[i0] = 1;  // slot 0 = self loop
  cur[i1] = 1;
  if (n0 < NN) {
    offs[n0] = base;
    wcsr[base] = make_uint2((uint)n0, __float_as_uint(dv0 * dv0));
  }
  if (n1 < NN) {
    offs[n1] = base + d0;
    wcsr[base + d0] = make_uint2((uint)n1, __float_as_uint(dv1 * dv1));
  }
  __syncthreads();
  int s = b * CAP;
  int n = min(gcur[b], CAP);
  for (int i = t; i < n; i += 256) {
    uint prk = pr_pack[s + i];
    int li = (int)(prk & (BSZ - 1));
    uint r = prk >> BSH;
    int p = atomicAdd(&cur[li], 1);
    wcsr[loff[li] + p] = make_uint2(r, __float_as_uint(dinv[r] * dl[li]));
  }
}

// ---------------- gemm64: t2[N,64](fp16) = h[N,128](fp16) @ W2 ----------------

__global__ __launch_bounds__(256) void k_gemm64(const _Float16* __restrict__ h, const _Float16* __restrict__ WT,
                                                _Float16* __restrict__ t2) {
  int wave = threadIdx.x >> 6, lane = threadIdx.x & 63;
  int col0 = wave * 16;
  int lr = lane & 15;
  int lk = (lane >> 4) * 8;
  hs8 bfrag[4];
#pragma unroll
  for (int ks = 0; ks < 4; ks++)
    bfrag[ks] = *(const hs8*)&WT[(size_t)(col0 + lr) * 128 + ks * 32 + lk];
  int row0 = blockIdx.x * 64;
#pragma unroll 1
  for (int mt = 0; mt < 4; mt++) {
    int r0 = row0 + mt * 16;
    if (r0 >= NN) return;
    const _Float16* hr = h + (size_t)(r0 + lr) * 128 + lk;
    f32x4 acc = {0.f, 0.f, 0.f, 0.f};
#pragma unroll
    for (int ks = 0; ks < 4; ks++) {
      hs8 af = *(const hs8*)&hr[ks * 32];
      acc = MFMA16H(af, bfrag[ks], acc);
    }
    int rbase = r0 + (lane >> 4) * 4;
#pragma unroll
    for (int r = 0; r < 4; r++)
      t2[(size_t)(rbase + r) * 64 + col0 + lr] = (_Float16)acc[r];
  }
}

// ---------------- aggregation (2 nodes/wave, 1-deep prefetch — round-10/11 proven form) ----------------

// layer 1: fp8 rows (128 B). half (32 lanes) per node; 2 subgroups of 16 per half.
__global__ __launch_bounds__(256) void k_agg128(const unsigned char* __restrict__ t8, const int* __restrict__ offs,
                                                const int* __restrict__ deg, const uint2* __restrict__ wcsr,
                                                const float* __restrict__ bias, _Float16* __restrict__ out) {
  int wave = threadIdx.x >> 6, lane = threadIdx.x & 63;
  int half = lane >> 5;          // 0: node A, 1: node B
  int sub = (lane >> 4) & 1;     // edge parity within half
  int f = lane & 15;             // feature lane (8 fp8 feats)
  int node = blockIdx.x * 8 + wave * 2 + half;
  int beg = offs[node];
  int d = deg[node];             // includes self-loop
  const char* tb = (const char*)t8;
  float acc[8] = {};
  int trips = (d + 1) >> 1;
  uint2 e = (sub < d) ? wcsr[beg + sub] : make_uint2(0u, 0u);
#pragma unroll 1
  for (int k = 0; k < trips; k++) {
    int ns = (k + 1) * 2 + sub;
    uint2 en = (ns < d) ? wcsr[beg + ns] : make_uint2(0u, 0u);
    float s = __uint_as_float(e.y);  // 0 for padded slots
    uint2 u = *(const uint2*)(tb + (((size_t)e.x) << 7) + (f << 3));
    f32x2 p0 = __builtin_amdgcn_cvt_pk_f32_fp8(u.x, false);
    f32x2 p1 = __builtin_amdgcn_cvt_pk_f32_fp8(u.x, true);
    f32x2 p2 = __builtin_amdgcn_cvt_pk_f32_fp8(u.y, false);
    f32x2 p3 = __builtin_amdgcn_cvt_pk_f32_fp8(u.y, true);
    acc[0] = fmaf(p0[0], s, acc[0]);
    acc[1] = fmaf(p0[1], s, acc[1]);
    acc[2] = fmaf(p1[0], s, acc[2]);
    acc[3] = fmaf(p1[1], s, acc[3]);
    acc[4] = fmaf(p2[0], s, acc[4]);
    acc[5] = fmaf(p2[1], s, acc[5]);
    acc[6] = fmaf(p3[0], s, acc[6]);
    acc[7] = fmaf(p3[1], s, acc[7]);
    e = en;
  }
#pragma unroll
  for (int j = 0; j < 8; j++) acc[j] += __shfl_xor(acc[j], 16);
  if (sub == 0) {
    float4 b0 = *(const float4*)&bias[f * 8];
    float4 b1 = *(const float4*)&bias[f * 8 + 4];
    h8u st;
    st.h[0] = (_Float16)fmaxf(acc[0] + b0.x, 0.f);
    st.h[1] = (_Float16)fmaxf(acc[1] + b0.y, 0.f);
    st.h[2] = (_Float16)fmaxf(acc[2] + b0.z, 0.f);
    st.h[3] = (_Float16)fmaxf(acc[3] + b0.w, 0.f);
    st.h[4] = (_Float16)fmaxf(acc[4] + b1.x, 0.f);
    st.h[5] = (_Float16)fmaxf(acc[5] + b1.y, 0.f);
    st.h[6] = (_Float16)fmaxf(acc[6] + b1.z, 0.f);
    st.h[7] = (_Float16)fmaxf(acc[7] + b1.w, 0.f);
    *(uint4*)&out[(size_t)node * 128 + f * 8] = st.q;
  }
}

// layer 2: fp16 rows (128 B). half (32 lanes) per node; 4 subgroups of 8 per half.
__global__ __launch_bounds__(256) void k_agg64(const _Float16* __restrict__ t, const int* __restrict__ offs,
                                               const int* __restrict__ deg, const uint2* __restrict__ wcsr,
                                               const float* __restrict__ bias, float* __restrict__ out) {
  int wave = threadIdx.x >> 6, lane = threadIdx.x & 63;
  int half = lane >> 5;
  int sub = (lane >> 3) & 3;     // edge slot within half
  int f8 = lane & 7;             // feature lane (8 fp16 feats)
  int node = blockIdx.x * 8 + wave * 2 + half;
  int beg = offs[node];
  int d = deg[node];
  const char* tb = (const char*)t;
  float acc[8] = {};
  int trips = (d + 3) >> 2;
  uint2 e = (sub < d) ? wcsr[beg + sub] : make_uint2(0u, 0u);
#pragma unroll 1
  for (int k = 0; k < trips; k++) {
    int ns = (k + 1) * 4 + sub;
    uint2 en = (ns < d) ? wcsr[beg + ns] : make_uint2(0u, 0u);
    float s = __uint_as_float(e.y);
    h8u u;
    u.q = *(const uint4*)(tb + (((size_t)e.x) << 7) + (f8 << 4));
    acc[0] = fmaf((float)u.h[0], s, acc[0]);
    acc[1] = fmaf((float)u.h[1], s, acc[1]);
    acc[2] = fmaf((float)u.h[2], s, acc[2]);
    acc[3] = fmaf((float)u.h[3], s, acc[3]);
    acc[4] = fmaf((float)u.h[4], s, acc[4]);
    acc[5] = fmaf((float)u.h[5], s, acc[5]);
    acc[6] = fmaf((float)u.h[6], s, acc[6]);
    acc[7] = fmaf((float)u.h[7], s, acc[7]);
    e = en;
  }
#pragma unroll
  for (int j = 0; j < 8; j++) {
    acc[j] += __shfl_xor(acc[j], 8);
    acc[j] += __shfl_xor(acc[j], 16);
  }
  if (sub == 0) {
    float4 b0 = *(const float4*)&bias[f8 * 8];
    float4 b1 = *(const float4*)&bias[f8 * 8 + 4];
    float4 o0 = make_float4(acc[0] + b0.x, acc[1] + b0.y, acc[2] + b0.z, acc[3] + b0.w);
    float4 o1 = make_float4(acc[4] + b1.x, acc[5] + b1.y, acc[6] + b1.z, acc[7] + b1.w);
    *(float4*)&out[(size_t)node * 64 + f8 * 8] = o0;
    *(float4*)&out[(size_t)node * 64 + f8 * 8 + 4] = o1;
  }
}

// ---------------- host ----------------

extern "C" void kernel_launch(void* const* d_in, const int* in_sizes, int n_in,
                              void* d_out, int out_size, void* d_ws, size_t ws_size,
                              hipStream_t stream) {
  const float* x  = (const float*)d_in[0];
  const int*   ei = (const int*)d_in[1];
  const float* W1 = (const float*)d_in[2];
  const float* b1 = (const float*)d_in[3];
  const float* W2 = (const float*)d_in[4];
  const float* b2 = (const float*)d_in[5];
  float* out = (float*)d_out;

  char* p = (char*)d_ws;
  int* gcur      = (int*)p;      p += alignup((size_t)NBUK * 4);   // |
  int* gctl      = (int*)p;      p += alignup(256);                 // | one contiguous memset region
  int* deg       = (int*)p;      p += alignup((size_t)NN * 4);
  int* offs      = (int*)p;      p += alignup((size_t)NN * 4);
  float* dinv    = (float*)p;    p += alignup((size_t)NN * 4);
  uint2* wcsr    = (uint2*)p;    p += alignup((size_t)(NE + NN + 64) * 8);
  _Float16* WT1  = (_Float16*)p; p += alignup(128 * 128 * 2);
  _Float16* WT2  = (_Float16*)p; p += alignup(64 * 128 * 2);
  unsigned char* t8 = (unsigned char*)p; p += alignup((size_t)NN * 128);
  _Float16* t2   = (_Float16*)p; p += alignup((size_t)NN * 64 * 2);
  _Float16* h1   = (_Float16*)p; p += alignup((size_t)NN * 128 * 2);
  // packed pair buffer aliases t2 (dead after k_bfill; t2 written by k_gemm64); 6.4 MB <= 12.8 MB
  uint* pr_pack  = (uint*)t2;
  (void)ws_size; (void)in_sizes; (void)n_in; (void)out_size;

  const int* row = ei;
  const int* col = ei + NE;

  int nbB = (NE + CHUNK - 1) / CHUNK;
  int nbG = (NN + 63) / 64;
  int nbA = NN / 8;

  hipMemsetAsync(gcur, 0, alignup((size_t)NBUK * 4) + 256, stream);
  k_bucket<<<nbB + 96, 256, 0, stream>>>(row, col, gcur, pr_pack, W1, WT1, W2, WT2, nbB);
  k_fbg<<<NBUK + nbG, 256, 0, stream>>>(pr_pack, gcur, deg, dinv, x, WT1, t8);
  k_bfill<<<NBUK, 256, 0, stream>>>(pr_pack, gcur, deg, dinv, gctl, offs, wcsr);
  k_agg128<<<nbA, 256, 0, stream>>>(t8, offs, deg, wcsr, b1, h1);
  k_gemm64<<<nbG, 256, 0, stream>>>(h1, WT2, t2);
  k_agg64<<<nbA, 256, 0, stream>>>(t2, offs, deg, wcsr, b2, out);
}